// Round 5
// baseline (445.222 us; speedup 1.0000x reference)
//
#include <hip/hip_runtime.h>
#include <math.h>

#define NB 8
#define NC 256
#define NHW 2304
#define NG 32
#define CPG 8            // NC / NG
#define GN_EPS 1e-5f
#define ATT_SCALE 0.0625f  // 1/sqrt(256)
#define PSTR 68            // P-tile LDS row stride (bf16)
#define XSTR 258           // xnT transpose LDS row stride (bf16), odd-dword
#define QSTR 68            // qkv epilogue LDS row stride (f32)

typedef __bf16 bf16x8 __attribute__((ext_vector_type(8)));
typedef __bf16 bf16x4 __attribute__((ext_vector_type(4)));
typedef float f32x4 __attribute__((ext_vector_type(4)));

#define MFMA(a, b, c) __builtin_amdgcn_mfma_f32_16x16x32_bf16(a, b, c, 0, 0, 0)

// ---------------------------------------------------------------------------
// Kernel 0: cast Wq/Wk/Wv fp32 -> bf16. grid (64, 3) x 256 threads.
// ---------------------------------------------------------------------------
__global__ __launch_bounds__(256) void k_wcast(
    const float* __restrict__ Wq, const float* __restrict__ Wk,
    const float* __restrict__ Wv, __bf16* __restrict__ Wqb,
    __bf16* __restrict__ Wkb, __bf16* __restrict__ Wvb) {
  const float* src = blockIdx.y == 0 ? Wq : (blockIdx.y == 1 ? Wk : Wv);
  __bf16* dst = blockIdx.y == 0 ? Wqb : (blockIdx.y == 1 ? Wkb : Wvb);
  int i = blockIdx.x * 256 + threadIdx.x;
  float4 v = ((const float4*)src)[i];
  bf16x4 o;
  o[0] = (__bf16)v.x; o[1] = (__bf16)v.y; o[2] = (__bf16)v.z; o[3] = (__bf16)v.w;
  ((bf16x4*)dst)[i] = o;
}

// ---------------------------------------------------------------------------
// Kernel 1: GroupNorm statistics -> per-channel scale/shift.
// grid NB*NG, 256 threads.
// ---------------------------------------------------------------------------
__global__ __launch_bounds__(256) void k_gn_stats(
    const float* __restrict__ x, const float* __restrict__ gn_w,
    const float* __restrict__ gn_b, float* __restrict__ scale,
    float* __restrict__ shift) {
  int bg = blockIdx.x;
  const float4* base = (const float4*)(x + (size_t)bg * CPG * NHW);
  const int n4 = CPG * NHW / 4;
  float s = 0.f, ss = 0.f;
  for (int i = threadIdx.x; i < n4; i += 256) {
    float4 v = base[i];
    s  += v.x + v.y + v.z + v.w;
    ss += v.x * v.x + v.y * v.y + v.z * v.z + v.w * v.w;
  }
  for (int off = 32; off > 0; off >>= 1) {
    s  += __shfl_down(s, off);
    ss += __shfl_down(ss, off);
  }
  __shared__ float red[8];
  int wv = threadIdx.x >> 6, ln = threadIdx.x & 63;
  if (ln == 0) { red[wv] = s; red[4 + wv] = ss; }
  __syncthreads();
  if (threadIdx.x < CPG) {
    float S  = red[0] + red[1] + red[2] + red[3];
    float SS = red[4] + red[5] + red[6] + red[7];
    const float inv_n = 1.f / (float)(CPG * NHW);
    float mean = S * inv_n;
    float var  = SS * inv_n - mean * mean;
    float rstd = rsqrtf(var + GN_EPS);
    int b = bg / NG, g = bg % NG;
    int c = g * CPG + threadIdx.x;
    float sc = gn_w[c] * rstd;
    scale[b * NC + c] = sc;
    shift[b * NC + c] = gn_b[c] - mean * sc;
  }
}

// ---------------------------------------------------------------------------
// Kernel 2: normalize + transpose x[c][p] fp32 -> xnT[p][c] bf16 via LDS.
// Reads c-major coalesced (256B/row-chunk), writes full 512B [p][c] rows.
// grid (NHW/64, NB), 256 threads. LDS 64 x 258 bf16 = 33 KB.
// ---------------------------------------------------------------------------
__global__ __launch_bounds__(256) void k_xnT(
    const float* __restrict__ x, const float* __restrict__ scale,
    const float* __restrict__ shift, __bf16* __restrict__ xnT) {
  __shared__ __bf16 t[64 * XSTR];
  int p0 = blockIdx.x * 64;
  int b = blockIdx.y;
  int w = threadIdx.x >> 6, lane = threadIdx.x & 63;
  const float* xb = x + (size_t)b * NC * NHW;
  const float* scb = scale + b * NC;
  const float* shb = shift + b * NC;
#pragma unroll 8
  for (int i = 0; i < 64; ++i) {
    int c = i * 4 + w;  // wave-uniform channel
    float v = xb[(size_t)c * NHW + p0 + lane] * scb[c] + shb[c];
    t[lane * XSTR + c] = (__bf16)v;  // 2-way b16 write (free)
  }
  __syncthreads();
  // store: per wave-instr 2 rows x 256B halves -> 16B/lane, coalesced
#pragma unroll
  for (int i = 0; i < 8; ++i) {
    int row = i * 8 + w * 2 + (lane >> 5);
    int c8 = (lane & 31) * 8;
    bf16x8 v8 = *(const bf16x8*)&t[row * XSTR + c8];
    *(bf16x8*)&xnT[((size_t)b * NHW + p0 + row) * NC + c8] = v8;
  }
}

// ---------------------------------------------------------------------------
// Kernel 3: QKV via MFMA; coalesced stores through an LDS-staged tile.
// Block: 4 waves; wave w: p-tile (pg*4+w)*16, o in [oq*64,+64).
// grid: 36 p-groups x 4 o-quarters x 8 b = 1152; b = blk&7 (XCD locality).
// ---------------------------------------------------------------------------
__global__ __launch_bounds__(256) void k_qkv(
    const __bf16* __restrict__ xnT,
    const __bf16* __restrict__ Wqb, const __bf16* __restrict__ Wkb,
    const __bf16* __restrict__ Wvb,
    const float* __restrict__ bq, const float* __restrict__ bk,
    const float* __restrict__ bv,
    __bf16* __restrict__ qT, __bf16* __restrict__ kT,
    __bf16* __restrict__ vbuf) {
  __shared__ float et[64 * QSTR];  // 17408 B staging tile
  int blk = blockIdx.x;
  int b = blk & 7;
  int r = blk >> 3;
  int oq = r & 3;
  int pg = r >> 2;
  int w = threadIdx.x >> 6;
  int lane = threadIdx.x & 63;
  int col = lane & 15, quad = lane >> 4;
  int p0w = (pg * 4 + w) * 16;   // this wave's p-tile
  int p0b = pg * 64;             // block's p range
  int o0 = oq * 64;

  const __bf16* xrow = xnT + ((size_t)b * NHW + p0w + col) * NC + quad * 8;
  bf16x8 xf[8];
#pragma unroll
  for (int ks = 0; ks < 8; ++ks) xf[ks] = *(const bf16x8*)(xrow + ks * 32);

  // ---- Q and K: D[m=o][n=p], staged to LDS [p][o], stored as [p][o] rows ----
#pragma unroll
  for (int t = 0; t < 2; ++t) {
    const __bf16* W = t == 0 ? Wqb : Wkb;
    const float* bias = t == 0 ? bq : bk;
    __bf16* dst = t == 0 ? qT : kT;
#pragma unroll
    for (int ot = 0; ot < 4; ++ot) {
      f32x4 acc = (f32x4){0.f, 0.f, 0.f, 0.f};
      const __bf16* wrow = W + ((size_t)(o0 + ot * 16 + col)) * NC + quad * 8;
#pragma unroll
      for (int ks = 0; ks < 8; ++ks) {
        bf16x8 wf = *(const bf16x8*)(wrow + ks * 32);
        acc = MFMA(wf, xf[ks], acc);
      }
      float4 b4 = *(const float4*)&bias[o0 + ot * 16 + quad * 4];
      f32x4 st = {acc[0] + b4.x, acc[1] + b4.y, acc[2] + b4.z, acc[3] + b4.w};
      // lane: row p = w*16+col, cols o = ot*16+quad*4..+4  (b128, uniform banks)
      *(f32x4*)&et[(w * 16 + col) * QSTR + ot * 16 + quad * 4] = st;
    }
    __syncthreads();
#pragma unroll
    for (int i = 0; i < 4; ++i) {
      int row = i * 16 + w * 4 + (lane >> 4);
      int c4 = (lane & 15) * 4;
      f32x4 v4 = *(const f32x4*)&et[row * QSTR + c4];
      bf16x4 s4;
#pragma unroll
      for (int j = 0; j < 4; ++j) s4[j] = (__bf16)v4[j];
      *(bf16x4*)&dst[((size_t)b * NHW + p0b + row) * NC + o0 + c4] = s4;
    }
    __syncthreads();
  }
  // ---- V: swapped operands -> D[m=p][n=o]; stage LDS [o][p]; store [c][p] ----
#pragma unroll
  for (int ot = 0; ot < 4; ++ot) {
    f32x4 acc = (f32x4){0.f, 0.f, 0.f, 0.f};
    const __bf16* wrow = Wvb + ((size_t)(o0 + ot * 16 + col)) * NC + quad * 8;
#pragma unroll
    for (int ks = 0; ks < 8; ++ks) {
      bf16x8 wf = *(const bf16x8*)(wrow + ks * 32);
      acc = MFMA(xf[ks], wf, acc);
    }
    float bvc = bv[o0 + ot * 16 + col];
    f32x4 st = {acc[0] + bvc, acc[1] + bvc, acc[2] + bvc, acc[3] + bvc};
    // lane: row o = ot*16+col, cols p = w*16+quad*4..+4
    *(f32x4*)&et[(ot * 16 + col) * QSTR + w * 16 + quad * 4] = st;
  }
  __syncthreads();
#pragma unroll
  for (int i = 0; i < 4; ++i) {
    int row = i * 16 + w * 4 + (lane >> 4);  // channel
    int c4 = (lane & 15) * 4;                // p offset
    f32x4 v4 = *(const f32x4*)&et[row * QSTR + c4];
    bf16x4 s4;
#pragma unroll
    for (int j = 0; j < 4; ++j) s4[j] = (__bf16)v4[j];
    *(bf16x4*)&vbuf[((size_t)b * NC + o0 + row) * NHW + p0b + c4] = s4;
  }
}

// ---------------------------------------------------------------------------
// Kernel 4: MFMA flash attention. 32 queries/block, 4 waves:
//   S: wq = w>>1 (16q half), wk = w&1 (32k half); Q resident in regs.
//   P: double-buffered LDS [32][68] bf16 -> ONE barrier per tile.
//   PV: channel split (wave owns 64 c) -> private O, no reduction.
// grid: 72 q-tiles x 8 b = 576 blocks (all resident at 4 blocks/CU cap).
// ---------------------------------------------------------------------------
__global__ __launch_bounds__(256, 4) void k_attn(
    const __bf16* __restrict__ qT, const __bf16* __restrict__ kT,
    const __bf16* __restrict__ vbuf, float* __restrict__ out) {
  __shared__ __bf16 p_lds[2][32 * PSTR];  // 2 x 4352 B
  __shared__ float l_red[2][32];
  int blk = blockIdx.x;
  int b = blk & 7;
  int q0 = (blk >> 3) * 32;
  int w = threadIdx.x >> 6;
  int wq = w >> 1, wk = w & 1;
  int lane = threadIdx.x & 63;
  int col = lane & 15, quad = lane >> 4;

  bf16x8 qf[8];  // A[m=q][k=c] for rows q0+wq*16..+16
  {
    const __bf16* qrow =
        qT + ((size_t)b * NHW + q0 + wq * 16 + col) * NC + quad * 8;
#pragma unroll
    for (int ks = 0; ks < 8; ++ks) qf[ks] = *(const bf16x8*)(qrow + ks * 32);
  }

  f32x4 oacc[4][2];  // [ct][qt]: c = w*64+ct*16+quad*4+reg, q = qt*16+col
#pragma unroll
  for (int ct = 0; ct < 4; ++ct)
#pragma unroll
    for (int qt = 0; qt < 2; ++qt) oacc[ct][qt] = (f32x4){0.f, 0.f, 0.f, 0.f};
  float lacc[4] = {0.f, 0.f, 0.f, 0.f};

  const __bf16* kbase = kT + ((size_t)b * NHW + wk * 32 + col) * NC + quad * 8;
  const __bf16* vbase = vbuf + ((size_t)b * NC + w * 64 + col) * NHW + quad * 8;

  int parity = 0;
  for (int kt = 0; kt < NHW; kt += 64, parity ^= 1) {
    // ---- S[16q x 32k] for this wave ----
    f32x4 sacc[2];
#pragma unroll
    for (int nt = 0; nt < 2; ++nt) sacc[nt] = (f32x4){0.f, 0.f, 0.f, 0.f};
    const __bf16* kp = kbase + (size_t)kt * NC;
#pragma unroll
    for (int nt = 0; nt < 2; ++nt)
#pragma unroll
      for (int ks = 0; ks < 8; ++ks) {
        bf16x8 kf = *(const bf16x8*)(kp + (size_t)nt * 16 * NC + ks * 32);
        sacc[nt] = MFMA(qf[ks], kf, sacc[nt]);
      }
    // ---- P = exp(S/16) -> LDS buffer [parity]; row-sum partials ----
    __bf16* pb = p_lds[parity];
#pragma unroll
    for (int reg = 0; reg < 4; ++reg) {
      float e0 = __expf(sacc[0][reg] * ATT_SCALE);
      float e1 = __expf(sacc[1][reg] * ATT_SCALE);
      int row = wq * 16 + quad * 4 + reg;
      pb[row * PSTR + wk * 32 + col] = (__bf16)e0;
      pb[row * PSTR + wk * 32 + 16 + col] = (__bf16)e1;
      float rs = e0 + e1;
      rs += __shfl_xor(rs, 1);
      rs += __shfl_xor(rs, 2);
      rs += __shfl_xor(rs, 4);
      rs += __shfl_xor(rs, 8);
      lacc[reg] += rs;
    }
    __syncthreads();  // P visible; also protects buffer[parity] reuse (t-2)
    // ---- O[c-slice] += V P^T ----
    const __bf16* vp = vbase + kt;
#pragma unroll
    for (int kc = 0; kc < 2; ++kc) {
      bf16x8 pf[2];
#pragma unroll
      for (int qt = 0; qt < 2; ++qt)
        pf[qt] = *(const bf16x8*)&pb[(qt * 16 + col) * PSTR + kc * 32 + quad * 8];
#pragma unroll
      for (int ct = 0; ct < 4; ++ct) {
        bf16x8 vf = *(const bf16x8*)(vp + (size_t)ct * 16 * NHW + kc * 32);
#pragma unroll
        for (int qt = 0; qt < 2; ++qt)
          oacc[ct][qt] = MFMA(vf, pf[qt], oacc[ct][qt]);
      }
    }
  }
  // ---- combine row sums across key halves ----
  if (col == 0) {
#pragma unroll
    for (int reg = 0; reg < 4; ++reg)
      l_red[wk][wq * 16 + quad * 4 + reg] = lacc[reg];
  }
  __syncthreads();
  float inv[2];
#pragma unroll
  for (int qt = 0; qt < 2; ++qt) {
    int qr = qt * 16 + col;
    inv[qt] = 1.f / (l_red[0][qr] + l_red[1][qr]);
  }
  float* ob = out + (size_t)b * NC * NHW + q0;
#pragma unroll
  for (int ct = 0; ct < 4; ++ct)
#pragma unroll
    for (int reg = 0; reg < 4; ++reg) {
      int c = w * 64 + ct * 16 + quad * 4 + reg;
#pragma unroll
      for (int qt = 0; qt < 2; ++qt)
        ob[(size_t)c * NHW + qt * 16 + col] = oacc[ct][qt][reg] * inv[qt];
    }
}

// ---------------------------------------------------------------------------
extern "C" void kernel_launch(void* const* d_in, const int* in_sizes, int n_in,
                              void* d_out, int out_size, void* d_ws,
                              size_t ws_size, hipStream_t stream) {
  const float* x   = (const float*)d_in[0];
  const float* Wq  = (const float*)d_in[1];
  const float* bq  = (const float*)d_in[2];
  const float* Wk  = (const float*)d_in[3];
  const float* bk  = (const float*)d_in[4];
  const float* Wv  = (const float*)d_in[5];
  const float* bv  = (const float*)d_in[6];
  const float* gnw = (const float*)d_in[7];
  const float* gnb = (const float*)d_in[8];
  float* out = (float*)d_out;

  const size_t per = (size_t)NB * NC * NHW;  // 4,718,592 elements
  char* wsb = (char*)d_ws;
  __bf16* xnT  = (__bf16*)wsb;
  __bf16* qT   = (__bf16*)(wsb + per * 2);
  __bf16* kT   = (__bf16*)(wsb + per * 4);
  __bf16* vbuf = (__bf16*)(wsb + per * 6);
  __bf16* Wqb  = (__bf16*)(wsb + per * 8);
  __bf16* Wkb  = Wqb + NC * NC;
  __bf16* Wvb  = Wkb + NC * NC;
  float* scale = (float*)(Wvb + NC * NC);
  float* shift = scale + NB * NC;

  hipLaunchKernelGGL(k_wcast, dim3(64, 3), dim3(256), 0, stream,
                     Wq, Wk, Wv, Wqb, Wkb, Wvb);
  hipLaunchKernelGGL(k_gn_stats, dim3(NB * NG), dim3(256), 0, stream,
                     x, gnw, gnb, scale, shift);
  hipLaunchKernelGGL(k_xnT, dim3(NHW / 64, NB), dim3(256), 0, stream,
                     x, scale, shift, xnT);
  hipLaunchKernelGGL(k_qkv, dim3(1152), dim3(256), 0, stream,
                     xnT, Wqb, Wkb, Wvb, bq, bk, bv, qT, kT, vbuf);
  hipLaunchKernelGGL(k_attn, dim3(576), dim3(256), 0, stream,
                     qT, kT, vbuf, out);
}

// Round 6
// 237.717 us; speedup vs baseline: 1.8729x; 1.8729x over previous
//
#include <hip/hip_runtime.h>
#include <math.h>

#define NB 8
#define NC 256
#define NHW 2304
#define NG 32
#define CPG 8
#define GN_EPS 1e-5f
#define ATT_SCALE 0.0625f
#define XSTR 258   // k_xnT transpose LDS stride (bf16)

typedef __bf16 bf16x8 __attribute__((ext_vector_type(8)));
typedef __bf16 bf16x4 __attribute__((ext_vector_type(4)));
typedef float f32x4 __attribute__((ext_vector_type(4)));

#define MFMA(a, b, c) __builtin_amdgcn_mfma_f32_16x16x32_bf16(a, b, c, 0, 0, 0)

__device__ __forceinline__ void async_lds16(const void* g, void* l) {
  __builtin_amdgcn_global_load_lds(
      (const __attribute__((address_space(1))) void*)g,
      (__attribute__((address_space(3))) void*)l, 16, 0, 0);
}

// ---------------------------------------------------------------------------
// Kernel 1: merged GN-stats (blocks 0..255) + W fp32->bf16 cast (256..447).
// ---------------------------------------------------------------------------
__global__ __launch_bounds__(256) void k_prep(
    const float* __restrict__ x, const float* __restrict__ gn_w,
    const float* __restrict__ gn_b, float* __restrict__ scale,
    float* __restrict__ shift,
    const float* __restrict__ Wq, const float* __restrict__ Wk,
    const float* __restrict__ Wv, __bf16* __restrict__ Wqb,
    __bf16* __restrict__ Wkb, __bf16* __restrict__ Wvb) {
  __shared__ float red[8];
  int blk = blockIdx.x;
  if (blk >= 256) {  // ---- weight cast ----
    int idx = blk - 256;
    int which = idx >> 6;
    const float* src = which == 0 ? Wq : (which == 1 ? Wk : Wv);
    __bf16* dst = which == 0 ? Wqb : (which == 1 ? Wkb : Wvb);
    int i = (idx & 63) * 256 + threadIdx.x;
    float4 v = ((const float4*)src)[i];
    bf16x4 o;
    o[0] = (__bf16)v.x; o[1] = (__bf16)v.y;
    o[2] = (__bf16)v.z; o[3] = (__bf16)v.w;
    ((bf16x4*)dst)[i] = o;
    return;
  }
  // ---- GroupNorm stats ----
  const float4* base = (const float4*)(x + (size_t)blk * CPG * NHW);
  const int n4 = CPG * NHW / 4;
  float s = 0.f, ss = 0.f;
  for (int i = threadIdx.x; i < n4; i += 256) {
    float4 v = base[i];
    s  += v.x + v.y + v.z + v.w;
    ss += v.x * v.x + v.y * v.y + v.z * v.z + v.w * v.w;
  }
  for (int off = 32; off > 0; off >>= 1) {
    s  += __shfl_down(s, off);
    ss += __shfl_down(ss, off);
  }
  int wv = threadIdx.x >> 6, ln = threadIdx.x & 63;
  if (ln == 0) { red[wv] = s; red[4 + wv] = ss; }
  __syncthreads();
  if (threadIdx.x < CPG) {
    float S  = red[0] + red[1] + red[2] + red[3];
    float SS = red[4] + red[5] + red[6] + red[7];
    const float inv_n = 1.f / (float)(CPG * NHW);
    float mean = S * inv_n;
    float var  = SS * inv_n - mean * mean;
    float rstd = rsqrtf(var + GN_EPS);
    int b = blk / NG, g = blk % NG;
    int c = g * CPG + threadIdx.x;
    float sc = gn_w[c] * rstd;
    scale[b * NC + c] = sc;
    shift[b * NC + c] = gn_b[c] - mean * sc;
  }
}

// ---------------------------------------------------------------------------
// Kernel 2: normalize + transpose x[c][p] fp32 -> xnT[p][c] bf16 via LDS.
// ---------------------------------------------------------------------------
__global__ __launch_bounds__(256) void k_xnT(
    const float* __restrict__ x, const float* __restrict__ scale,
    const float* __restrict__ shift, __bf16* __restrict__ xnT) {
  __shared__ __bf16 t[64 * XSTR];
  int p0 = blockIdx.x * 64;
  int b = blockIdx.y;
  int w = threadIdx.x >> 6, lane = threadIdx.x & 63;
  const float* xb = x + (size_t)b * NC * NHW;
  const float* scb = scale + b * NC;
  const float* shb = shift + b * NC;
#pragma unroll 8
  for (int i = 0; i < 64; ++i) {
    int c = i * 4 + w;
    float v = xb[(size_t)c * NHW + p0 + lane] * scb[c] + shb[c];
    t[lane * XSTR + c] = (__bf16)v;
  }
  __syncthreads();
#pragma unroll
  for (int i = 0; i < 8; ++i) {
    int row = i * 8 + w * 2 + (lane >> 5);
    int c8 = (lane & 31) * 8;
    bf16x8 v8 = *(const bf16x8*)&t[row * XSTR + c8];
    *(bf16x8*)&xnT[((size_t)b * NHW + p0 + row) * NC + c8] = v8;
  }
}

// ---------------------------------------------------------------------------
// Kernel 3: QKV GEMM. Block: 128p x 64o, 4 waves m-split (32p each).
// One xf fragment set feeds all three GEMMs; LDS-transposed coalesced stores.
// grid: 18pg x 4oq x 8b = 576; b = blk&7 (XCD locality).
// ---------------------------------------------------------------------------
__global__ __launch_bounds__(256) void k_qkv(
    const __bf16* __restrict__ xnT,
    const __bf16* __restrict__ Wqb, const __bf16* __restrict__ Wkb,
    const __bf16* __restrict__ Wvb,
    const float* __restrict__ bq, const float* __restrict__ bk,
    const float* __restrict__ bv,
    __bf16* __restrict__ qT, __bf16* __restrict__ kT,
    __bf16* __restrict__ vbuf) {
  __shared__ __bf16 tile[9216];  // q/k: [128][72]; v: [64][136]
  int blk = blockIdx.x;
  int b = blk & 7;
  int r = blk >> 3;
  int oq = r & 3;
  int pg = r >> 2;
  int p0 = pg * 128, o0 = oq * 64;
  int tid = threadIdx.x;
  int w = tid >> 6, lane = tid & 63;
  int col = lane & 15, quad = lane >> 4;

  const __bf16* xrow =
      xnT + ((size_t)b * NHW + p0 + w * 32 + col) * NC + quad * 8;
  bf16x8 xf[2][8];
#pragma unroll
  for (int mt = 0; mt < 2; ++mt)
#pragma unroll
    for (int ks = 0; ks < 8; ++ks)
      xf[mt][ks] = *(const bf16x8*)(xrow + (size_t)mt * 16 * NC + ks * 32);

#pragma unroll
  for (int t = 0; t < 3; ++t) {
    const __bf16* W = t == 0 ? Wqb : (t == 1 ? Wkb : Wvb);
    const float* bias = t == 0 ? bq : (t == 1 ? bk : bv);
    f32x4 acc[2][4];
#pragma unroll
    for (int mt = 0; mt < 2; ++mt)
#pragma unroll
      for (int nt = 0; nt < 4; ++nt) acc[mt][nt] = (f32x4){0.f, 0.f, 0.f, 0.f};
#pragma unroll
    for (int nt = 0; nt < 4; ++nt) {
      const __bf16* wrow = W + ((size_t)(o0 + nt * 16 + col)) * NC + quad * 8;
#pragma unroll
      for (int ks = 0; ks < 8; ++ks) {
        bf16x8 wf = *(const bf16x8*)(wrow + ks * 32);
        acc[0][nt] = MFMA(xf[0][ks], wf, acc[0][nt]);
        acc[1][nt] = MFMA(xf[1][ks], wf, acc[1][nt]);
      }
    }
    if (t > 0) __syncthreads();  // previous tile reads done
    if (t < 2) {
      // stage D[p][o] + bias -> tile[128][72]
#pragma unroll
      for (int mt = 0; mt < 2; ++mt)
#pragma unroll
        for (int nt = 0; nt < 4; ++nt) {
          float bc = bias[o0 + nt * 16 + col];
#pragma unroll
          for (int reg = 0; reg < 4; ++reg) {
            int row = w * 32 + mt * 16 + quad * 4 + reg;
            tile[row * 72 + nt * 16 + col] = (__bf16)(acc[mt][nt][reg] + bc);
          }
        }
      __syncthreads();
      __bf16* dst = t == 0 ? qT : kT;
#pragma unroll
      for (int pass = 0; pass < 4; ++pass) {
        int unit = pass * 256 + tid;
        int row = unit >> 3, ch = unit & 7;
        bf16x8 v8 = *(const bf16x8*)&tile[row * 72 + ch * 8];
        *(bf16x8*)&dst[((size_t)b * NHW + p0 + row) * NC + o0 + ch * 8] = v8;
      }
    } else {
      // V: stage transposed [o][p] -> tile[64][136]
#pragma unroll
      for (int mt = 0; mt < 2; ++mt)
#pragma unroll
        for (int nt = 0; nt < 4; ++nt) {
          float bc = bias[o0 + nt * 16 + col];
#pragma unroll
          for (int reg = 0; reg < 4; ++reg) {
            int p = w * 32 + mt * 16 + quad * 4 + reg;
            tile[(nt * 16 + col) * 136 + p] = (__bf16)(acc[mt][nt][reg] + bc);
          }
        }
      __syncthreads();
#pragma unroll
      for (int pass = 0; pass < 4; ++pass) {
        int unit = pass * 256 + tid;
        int row = unit >> 4, ch = unit & 15;  // row = o-local, ch = 16B p-chunk
        bf16x8 v8 = *(const bf16x8*)&tile[row * 136 + ch * 8];
        *(bf16x8*)&vbuf[((size_t)b * NC + o0 + row) * NHW + p0 + ch * 8] = v8;
      }
    }
  }
}

// ---------------------------------------------------------------------------
// Kernel 4: stage A — S = Q K^T (128q x 64k per block), P = exp(S/16) -> HBM,
// row-sum partials via atomicAdd. K-tile staged once via global_load_lds with
// XOR-swizzled LDS (conflict-free frag reads). grid 18qg x 36kt x 8b = 5184.
// ---------------------------------------------------------------------------
__global__ __launch_bounds__(256, 3) void k_sexp(
    const __bf16* __restrict__ qT, const __bf16* __restrict__ kT,
    __bf16* __restrict__ P, float* __restrict__ lsum) {
  __shared__ __bf16 sk[64 * 256];  // 32 KB; P-transpose tile aliases it
  __bf16* pt = sk;                 // [128][72] bf16 = 18432 B
  int blk = blockIdx.x;
  int b = blk & 7;
  int r = blk >> 3;
  int kt = r % 36;
  int qg = r / 36;
  int q0 = qg * 128, k0 = kt * 64;
  int tid = threadIdx.x;
  int w = tid >> 6, lane = tid & 63;
  int col = lane & 15, quad = lane >> 4;

  // ---- stage K tile: wave w rows [w*16, +16), 8 instr x 2 rows ----
  {
    int sub = lane >> 5;           // 0/1: which row of the pair
    int p5 = lane & 31;            // LDS 16B-chunk position within row
#pragma unroll
    for (int j = 0; j < 8; ++j) {
      int r0 = w * 16 + j * 2;
      int rloc = r0 + sub;
      int g = p5 ^ (rloc & 7);     // swizzled global chunk
      const __bf16* gp = kT + ((size_t)b * NHW + k0 + rloc) * NC + g * 8;
      async_lds16(gp, (void*)&sk[r0 * 256]);
    }
  }
  // ---- Q fragments (direct) ----
  const __bf16* qrow =
      qT + ((size_t)b * NHW + q0 + w * 32 + col) * NC + quad * 8;
  bf16x8 qf[2][8];
#pragma unroll
  for (int mt = 0; mt < 2; ++mt)
#pragma unroll
    for (int ks = 0; ks < 8; ++ks)
      qf[mt][ks] = *(const bf16x8*)(qrow + (size_t)mt * 16 * NC + ks * 32);
  __syncthreads();  // staging + (implicit vmcnt0) done

  f32x4 sacc[2][4];
#pragma unroll
  for (int mt = 0; mt < 2; ++mt)
#pragma unroll
    for (int nt = 0; nt < 4; ++nt) sacc[mt][nt] = (f32x4){0.f, 0.f, 0.f, 0.f};
  int c7 = col & 7;
#pragma unroll
  for (int nt = 0; nt < 4; ++nt) {
    int rrow = nt * 16 + col;
#pragma unroll
    for (int ks = 0; ks < 8; ++ks) {
      int c = ks * 4 + quad;
      bf16x8 kf = *(const bf16x8*)&sk[rrow * 256 + ((c ^ c7) << 3)];
      sacc[0][nt] = MFMA(qf[0][ks], kf, sacc[0][nt]);
      sacc[1][nt] = MFMA(qf[1][ks], kf, sacc[1][nt]);
    }
  }
  // ---- exp (in place) + row-sum partials -> atomicAdd ----
#pragma unroll
  for (int mt = 0; mt < 2; ++mt)
#pragma unroll
    for (int reg = 0; reg < 4; ++reg) {
      float rs = 0.f;
#pragma unroll
      for (int nt = 0; nt < 4; ++nt) {
        float e = __expf(sacc[mt][nt][reg] * ATT_SCALE);
        sacc[mt][nt][reg] = e;
        rs += e;
      }
      rs += __shfl_xor(rs, 1);
      rs += __shfl_xor(rs, 2);
      rs += __shfl_xor(rs, 4);
      rs += __shfl_xor(rs, 8);
      if (col == 0) {
        int row = w * 32 + mt * 16 + quad * 4 + reg;
        atomicAdd(&lsum[(size_t)b * NHW + q0 + row], rs);
      }
    }
  __syncthreads();  // all sk reads complete before pt overwrite
#pragma unroll
  for (int mt = 0; mt < 2; ++mt)
#pragma unroll
    for (int nt = 0; nt < 4; ++nt)
#pragma unroll
      for (int reg = 0; reg < 4; ++reg) {
        int row = w * 32 + mt * 16 + quad * 4 + reg;
        pt[row * 72 + nt * 16 + col] = (__bf16)sacc[mt][nt][reg];
      }
  __syncthreads();
#pragma unroll
  for (int pass = 0; pass < 4; ++pass) {
    int unit = pass * 256 + tid;
    int row = unit >> 3, ch = unit & 7;
    bf16x8 v8 = *(const bf16x8*)&pt[row * 72 + ch * 8];
    *(bf16x8*)&P[((size_t)b * NHW + q0 + row) * NHW + k0 + ch * 8] = v8;
  }
}

// ---------------------------------------------------------------------------
// Kernel 5: stage B — out[c][q] = (V x P^T)[c][q] / lsum[q].
// Block: 64c x 144q, 4 waves m-split (16c). P staged via global_load_lds into
// triple-buffered swizzled LDS; raw vmcnt(N)+s_barrier keeps prefetch in
// flight across the barrier. grid: 4cq x 16qg x 8b = 512 = exactly 2/CU.
// ---------------------------------------------------------------------------
__global__ __launch_bounds__(256, 4) void k_pv(
    const __bf16* __restrict__ P, const __bf16* __restrict__ vbuf,
    const float* __restrict__ lsum, float* __restrict__ out) {
  __shared__ __bf16 sp[3][144 * 64];  // 3 x 18432 B, XOR-swizzled rows
  int blk = blockIdx.x;
  int b = blk & 7;
  int r = blk >> 3;
  int cq = r & 3;
  int qg = r >> 2;
  int q0 = qg * 144;
  int tid = threadIdx.x;
  int w = tid >> 6, lane = tid & 63;
  int col = lane & 15, quad = lane >> 4;
  int c0 = cq * 64 + w * 16;

  // staging lane constants: rows j*8 + (lane>>3), chunk pos lane&7
  int sub = lane >> 3;
  int gsw = (lane & 7) ^ (sub & 7);  // swizzled global chunk
  const __bf16* pbase = P + ((size_t)b * NHW + q0) * NHW;

  f32x4 acc[9];
#pragma unroll
  for (int nt = 0; nt < 9; ++nt) acc[nt] = (f32x4){0.f, 0.f, 0.f, 0.f};

  const __bf16* vbase =
      vbuf + ((size_t)b * NC + c0 + col) * NHW + quad * 8;
  int c7 = col & 7;

  // prologue: stage iter 0 into buffer 0
  for (int j = w; j < 18; j += 4) {
    const __bf16* gp = pbase + (size_t)(j * 8 + sub) * NHW + gsw * 8;
    async_lds16(gp, (void*)&sp[0][j * 512]);
  }
  for (int it = 0; it < 36; ++it) {
    const __bf16* buf = sp[it % 3];
    if (it < 35) {
      __bf16* nbuf = sp[(it + 1) % 3];
      const __bf16* pn = pbase + (size_t)(it + 1) * 64;
      for (int j = w; j < 18; j += 4) {
        const __bf16* gp = pn + (size_t)(j * 8 + sub) * NHW + gsw * 8;
        async_lds16(gp, (void*)&nbuf[j * 512]);
      }
      if (w < 2)
        asm volatile("s_waitcnt vmcnt(5)\n\ts_barrier" ::: "memory");
      else
        asm volatile("s_waitcnt vmcnt(4)\n\ts_barrier" ::: "memory");
    } else {
      asm volatile("s_waitcnt vmcnt(0)\n\ts_barrier" ::: "memory");
    }
    const __bf16* vp = vbase + it * 64;
#pragma unroll
    for (int ks = 0; ks < 2; ++ks) {
      bf16x8 vf = *(const bf16x8*)(vp + ks * 32);
      int c = ks * 4 + quad;
#pragma unroll
      for (int nt = 0; nt < 9; ++nt) {
        int row = nt * 16 + col;
        bf16x8 pf = *(const bf16x8*)&buf[row * 64 + ((c ^ c7) << 3)];
        acc[nt] = MFMA(vf, pf, acc[nt]);
      }
    }
  }
  // ---- normalize + store ----
  float* ob = out + (size_t)b * NC * NHW;
#pragma unroll
  for (int nt = 0; nt < 9; ++nt) {
    float inv = 1.f / lsum[(size_t)b * NHW + q0 + nt * 16 + col];
#pragma unroll
    for (int reg = 0; reg < 4; ++reg) {
      int c = c0 + quad * 4 + reg;
      ob[(size_t)c * NHW + q0 + nt * 16 + col] = acc[nt][reg] * inv;
    }
  }
}

// ---------------------------------------------------------------------------
extern "C" void kernel_launch(void* const* d_in, const int* in_sizes, int n_in,
                              void* d_out, int out_size, void* d_ws,
                              size_t ws_size, hipStream_t stream) {
  const float* x   = (const float*)d_in[0];
  const float* Wq  = (const float*)d_in[1];
  const float* bq  = (const float*)d_in[2];
  const float* Wk  = (const float*)d_in[3];
  const float* bk  = (const float*)d_in[4];
  const float* Wv  = (const float*)d_in[5];
  const float* bv  = (const float*)d_in[6];
  const float* gnw = (const float*)d_in[7];
  const float* gnb = (const float*)d_in[8];
  float* out = (float*)d_out;

  const size_t per = (size_t)NB * NC * NHW;          // 4,718,592 elems
  const size_t psz = (size_t)NB * NHW * NHW * 2;     // 84,934,656 B
  char* wsb = (char*)d_ws;
  __bf16* qT   = (__bf16*)wsb;
  __bf16* kT   = (__bf16*)(wsb + per * 2);
  __bf16* vbuf = (__bf16*)(wsb + per * 4);
  __bf16* xnT  = (__bf16*)(wsb + per * 6);  // dead after k_qkv
  __bf16* P    = (__bf16*)(wsb + per * 6);  // aliases xnT region, 85 MB
  char* tail   = wsb + per * 6 + psz;
  __bf16* Wqb  = (__bf16*)tail;
  __bf16* Wkb  = Wqb + NC * NC;
  __bf16* Wvb  = Wkb + NC * NC;
  float* scale = (float*)(Wvb + NC * NC);
  float* shift = scale + NB * NC;
  float* lsum  = shift + NB * NC;           // NB*NHW floats

  hipMemsetAsync(lsum, 0, (size_t)NB * NHW * sizeof(float), stream);
  hipLaunchKernelGGL(k_prep, dim3(448), dim3(256), 0, stream,
                     x, gnw, gnb, scale, shift, Wq, Wk, Wv, Wqb, Wkb, Wvb);
  hipLaunchKernelGGL(k_xnT, dim3(NHW / 64, NB), dim3(256), 0, stream,
                     x, scale, shift, xnT);
  hipLaunchKernelGGL(k_qkv, dim3(576), dim3(256), 0, stream,
                     xnT, Wqb, Wkb, Wvb, bq, bk, bv, qT, kT, vbuf);
  hipLaunchKernelGGL(k_sexp, dim3(5184), dim3(256), 0, stream,
                     qT, kT, P, lsum);
  hipLaunchKernelGGL(k_pv, dim3(512), dim3(256), 0, stream,
                     P, vbuf, lsum, out);
}